// Round 6
// baseline (207.260 us; speedup 1.0000x reference)
//
#include <hip/hip_runtime.h>
#include <stdint.h>

#define N_NODES 50000
#define N_EDGES 800000
#define F_IN    512
#define F_HID   128
#define F_OUT   3
#define NBLK_SCAN 196  // ceil(50000/256)

typedef __attribute__((ext_vector_type(8))) short short8;
typedef __attribute__((ext_vector_type(4))) float f32x4;

__device__ __forceinline__ unsigned short f2bf(float f) {
  union { float f; unsigned u; } v; v.f = f;
  unsigned r = v.u + 0x7FFFu + ((v.u >> 16) & 1u);
  return (unsigned short)(r >> 16);
}

// ---- CSR build -----------------------------------------------------------
__global__ __launch_bounds__(256) void k_zero(int* __restrict__ count) {
  int i = blockIdx.x * 256 + threadIdx.x;
  if (i < N_NODES) count[i] = 0;
}

__global__ __launch_bounds__(256) void k_hist(const int* __restrict__ dst,
                                              int* __restrict__ count) {
  int e = blockIdx.x * 256 + threadIdx.x;
  if (e < N_EDGES) atomicAdd(&count[dst[e]], 1);
}

// hierarchical scan, stage 1: per-block exclusive prefix + block sums
__global__ __launch_bounds__(256) void k_scan1(const int* __restrict__ count,
                                               int* __restrict__ local_pre,
                                               int* __restrict__ blocksum) {
  __shared__ int s[256];
  int t = threadIdx.x;
  int i = blockIdx.x * 256 + t;
  int v = (i < N_NODES) ? count[i] : 0;
  s[t] = v;
  __syncthreads();
  #pragma unroll
  for (int off = 1; off < 256; off <<= 1) {
    int u = (t >= off) ? s[t - off] : 0;
    __syncthreads();
    s[t] += u;
    __syncthreads();
  }
  if (i < N_NODES) local_pre[i] = s[t] - v;  // exclusive
  if (t == 255) blocksum[blockIdx.x] = s[255];
}

// stage 2: single small block scans the 196 block sums (exclusive)
__global__ __launch_bounds__(256) void k_scan2(const int* __restrict__ blocksum,
                                               int* __restrict__ blockoff) {
  __shared__ int s[256];
  int t = threadIdx.x;
  int v = (t < NBLK_SCAN) ? blocksum[t] : 0;
  s[t] = v;
  __syncthreads();
  #pragma unroll
  for (int off = 1; off < 256; off <<= 1) {
    int u = (t >= off) ? s[t - off] : 0;
    __syncthreads();
    s[t] += u;
    __syncthreads();
  }
  if (t < NBLK_SCAN) blockoff[t] = s[t] - v;
}

// stage 3: finalize row_ptr / cursor / dinv
__global__ __launch_bounds__(256) void k_scan3(const int* __restrict__ count,
                                               const int* __restrict__ local_pre,
                                               const int* __restrict__ blockoff,
                                               int* __restrict__ row_ptr,
                                               int* __restrict__ cursor,
                                               float* __restrict__ dinv) {
  int i = blockIdx.x * 256 + threadIdx.x;
  if (i < N_NODES) {
    int r = local_pre[i] + blockoff[blockIdx.x];
    row_ptr[i] = r;
    cursor[i]  = r;
    dinv[i] = rsqrtf((float)(count[i] + 1));
  }
  if (i == 0) row_ptr[N_NODES] = N_EDGES;
}

__global__ __launch_bounds__(256) void k_fill(const int* __restrict__ src,
                                              const int* __restrict__ dst,
                                              int* __restrict__ cursor,
                                              int* __restrict__ csr_src) {
  int e = blockIdx.x * 256 + threadIdx.x;
  if (e >= N_EDGES) return;
  int d = dst[e];
  int pos = atomicAdd(&cursor[d], 1);
  csr_src[pos] = src[e];
}

// ---- W1 -> bf16, transposed to [n][k] ------------------------------------
__global__ __launch_bounds__(256) void k_w1t(const float* __restrict__ W1,
                                             unsigned short* __restrict__ W1t) {
  int idx = blockIdx.x * 256 + threadIdx.x;
  if (idx < F_IN * F_HID) {
    int k = idx >> 7;    // W1 is [512][128] row-major
    int n = idx & 127;
    W1t[n * F_IN + k] = f2bf(W1[idx]);
  }
}

// ---- GEMM1: h1 = x @ W1 (bf16 MFMA, f32 acc), h1 stored bf16 --------------
#define BM 128
#define BK 64
#define LPAD 72  // 144 B/row breaks the stride-128B bank conflict

__global__ __launch_bounds__(256) void k_gemm1(const float* __restrict__ x,
                                               const unsigned short* __restrict__ W1t,
                                               unsigned short* __restrict__ h1b) {
  __shared__ unsigned short As[BM * LPAD];
  __shared__ unsigned short Bs[F_HID * LPAD];
  const int t = threadIdx.x;
  const int lane = t & 63;
  const int wid = t >> 6;
  const int row0 = blockIdx.x * BM;

  f32x4 acc[2][8];
  #pragma unroll
  for (int i = 0; i < 2; ++i)
    #pragma unroll
    for (int j = 0; j < 8; ++j) acc[i][j] = (f32x4)0.0f;

  const int lane15 = lane & 15;
  const int kgrp = (lane >> 4) << 3;
  const int wrow = wid << 5;

  for (int k0 = 0; k0 < F_IN; k0 += BK) {
    #pragma unroll
    for (int r = 0; r < 8; ++r) {
      int f = (r << 8) + t;
      int row = f >> 4;
      int c4 = (f & 15) << 2;
      int grow = row0 + row;
      grow = grow < N_NODES ? grow : N_NODES - 1;  // clamp tail (store guarded)
      const float4 v = *reinterpret_cast<const float4*>(x + (size_t)grow * F_IN + k0 + c4);
      ushort4 b;
      b.x = f2bf(v.x); b.y = f2bf(v.y); b.z = f2bf(v.z); b.w = f2bf(v.w);
      *reinterpret_cast<ushort4*>(&As[row * LPAD + c4]) = b;
    }
    #pragma unroll
    for (int r = 0; r < 8; ++r) {
      int g = (r << 8) + t;
      int n = g >> 4;
      int c4 = (g & 15) << 2;
      ushort4 wv = *reinterpret_cast<const ushort4*>(W1t + n * F_IN + k0 + c4);
      *reinterpret_cast<ushort4*>(&Bs[n * LPAD + c4]) = wv;
    }
    __syncthreads();
    #pragma unroll
    for (int ks = 0; ks < 2; ++ks) {
      const int kk = (ks << 5) + kgrp;
      short8 a0 = *reinterpret_cast<const short8*>(&As[(wrow + lane15) * LPAD + kk]);
      short8 a1 = *reinterpret_cast<const short8*>(&As[(wrow + 16 + lane15) * LPAD + kk]);
      #pragma unroll
      for (int nr = 0; nr < 8; ++nr) {
        short8 b = *reinterpret_cast<const short8*>(&Bs[(nr * 16 + lane15) * LPAD + kk]);
        acc[0][nr] = __builtin_amdgcn_mfma_f32_16x16x32_bf16(a0, b, acc[0][nr], 0, 0, 0);
        acc[1][nr] = __builtin_amdgcn_mfma_f32_16x16x32_bf16(a1, b, acc[1][nr], 0, 0, 0);
      }
    }
    __syncthreads();
  }
  const int rgrp = (lane >> 4) << 2;
  #pragma unroll
  for (int mr = 0; mr < 2; ++mr) {
    const int rowb = row0 + wrow + mr * 16 + rgrp;
    #pragma unroll
    for (int nr = 0; nr < 8; ++nr) {
      const int col = nr * 16 + lane15;
      #pragma unroll
      for (int r = 0; r < 4; ++r) {
        const int row = rowb + r;
        if (row < N_NODES) h1b[(size_t)row * F_HID + col] = f2bf(acc[mr][nr][r]);
      }
    }
  }
}

// ---- layer-1 gather + bias + ReLU + GEMM2 fused: wave per node ------------
// R3/R5-proven shape: two 32-lane groups, lane (l&31) owns 4 features,
// groups take alternate edges, unroll-2. ONLY change vs R5: row payload is
// bf16 -> uint2 loads (8 B/lane, dwordx2) + bit-unpack. Halves gather bytes.
__global__ __launch_bounds__(256) void k_agg1_fused(const int* __restrict__ row_ptr,
                                                    const int* __restrict__ csr_src,
                                                    const float* __restrict__ dinv,
                                                    const unsigned short* __restrict__ h1b,
                                                    const float* __restrict__ b1,
                                                    const float* __restrict__ W2,
                                                    float* __restrict__ t2) {
  int t = threadIdx.x;
  int lane = t & 63;
  int node = blockIdx.x * 4 + (t >> 6);  // 50000 = 12500*4, no tail
  int g = lane >> 5;
  int fl = (lane & 31) << 2;
  float dd = dinv[node];
  f32x4 acc = (f32x4)0.0f;
  if (g == 0) {  // self loop
    const uint2 sv = *reinterpret_cast<const uint2*>(h1b + (size_t)node * F_HID + fl);
    float w = dd * dd;
    acc[0] = w * __uint_as_float(sv.x << 16);
    acc[1] = w * __uint_as_float(sv.x & 0xFFFF0000u);
    acc[2] = w * __uint_as_float(sv.y << 16);
    acc[3] = w * __uint_as_float(sv.y & 0xFFFF0000u);
  }
  int start = row_ptr[node], end = row_ptr[node + 1];
  int i = start + g;
  // unrolled-by-2: edges i and i+2 independent -> 2 rows in flight per group
  for (; i + 2 < end; i += 4) {
    int s0 = csr_src[i];
    int s1 = csr_src[i + 2];
    const uint2 v0 = *reinterpret_cast<const uint2*>(h1b + (size_t)s0 * F_HID + fl);
    const uint2 v1 = *reinterpret_cast<const uint2*>(h1b + (size_t)s1 * F_HID + fl);
    float w0 = dinv[s0] * dd;
    float w1 = dinv[s1] * dd;
    acc[0] += w0 * __uint_as_float(v0.x << 16);
    acc[1] += w0 * __uint_as_float(v0.x & 0xFFFF0000u);
    acc[2] += w0 * __uint_as_float(v0.y << 16);
    acc[3] += w0 * __uint_as_float(v0.y & 0xFFFF0000u);
    acc[0] += w1 * __uint_as_float(v1.x << 16);
    acc[1] += w1 * __uint_as_float(v1.x & 0xFFFF0000u);
    acc[2] += w1 * __uint_as_float(v1.y << 16);
    acc[3] += w1 * __uint_as_float(v1.y & 0xFFFF0000u);
  }
  for (; i < end; i += 2) {
    int s = csr_src[i];
    float w = dinv[s] * dd;
    const uint2 v = *reinterpret_cast<const uint2*>(h1b + (size_t)s * F_HID + fl);
    acc[0] += w * __uint_as_float(v.x << 16);
    acc[1] += w * __uint_as_float(v.x & 0xFFFF0000u);
    acc[2] += w * __uint_as_float(v.y << 16);
    acc[3] += w * __uint_as_float(v.y & 0xFFFF0000u);
  }
  // combine the two edge-groups: lanes 0-31 += lanes 32-63
  #pragma unroll
  for (int j = 0; j < 4; ++j) {
    float o = __shfl(acc[j], (lane & 31) + 32);
    acc[j] += o;
  }
  // bias + relu (valid on lanes 0-31)
  const float4 bb = *reinterpret_cast<const float4*>(b1 + fl);
  float v0 = fmaxf(acc[0] + bb.x, 0.0f);
  float v1 = fmaxf(acc[1] + bb.y, 0.0f);
  float v2 = fmaxf(acc[2] + bb.z, 0.0f);
  float v3 = fmaxf(acc[3] + bb.w, 0.0f);
  // 128->3 dot products; W2 is [128][3] row-major
  const float* w2r = W2 + fl * 3;
  #pragma unroll
  for (int c = 0; c < 3; ++c) {
    float p = v0 * w2r[c] + v1 * w2r[3 + c] + v2 * w2r[6 + c] + v3 * w2r[9 + c];
    p += __shfl_down(p, 16);
    p += __shfl_down(p, 8);
    p += __shfl_down(p, 4);
    p += __shfl_down(p, 2);
    p += __shfl_down(p, 1);
    if (lane == 0) t2[(size_t)node * 3 + c] = p;
  }
}

// ---- layer-2 gather: 16 lanes per node ------------------------------------
__global__ __launch_bounds__(256) void k_agg2(const int* __restrict__ row_ptr,
                                              const int* __restrict__ csr_src,
                                              const float* __restrict__ dinv,
                                              const float* __restrict__ t2,
                                              const float* __restrict__ b2,
                                              float* __restrict__ out) {
  int t = threadIdx.x;
  int node = blockIdx.x * 16 + (t >> 4);
  if (node >= N_NODES) return;
  int sl = t & 15;
  float dd = dinv[node];
  float a0 = 0.f, a1 = 0.f, a2 = 0.f;
  int start = row_ptr[node], end = row_ptr[node + 1];
  for (int i = start + sl; i < end; i += 16) {
    int s = csr_src[i];
    float w = dinv[s] * dd;
    a0 += w * t2[s * 3 + 0];
    a1 += w * t2[s * 3 + 1];
    a2 += w * t2[s * 3 + 2];
  }
  #pragma unroll
  for (int off = 8; off > 0; off >>= 1) {
    a0 += __shfl_down(a0, off);
    a1 += __shfl_down(a1, off);
    a2 += __shfl_down(a2, off);
  }
  if (sl == 0) {
    float w = dd * dd;
    out[node * 3 + 0] = b2[0] + w * t2[node * 3 + 0] + a0;
    out[node * 3 + 1] = b2[1] + w * t2[node * 3 + 1] + a1;
    out[node * 3 + 2] = b2[2] + w * t2[node * 3 + 2] + a2;
  }
}

extern "C" void kernel_launch(void* const* d_in, const int* in_sizes, int n_in,
                              void* d_out, int out_size, void* d_ws, size_t ws_size,
                              hipStream_t stream) {
  const float* x  = (const float*)d_in[0];
  const int*   ei = (const int*)d_in[1];
  const float* W1 = (const float*)d_in[2];
  const float* b1 = (const float*)d_in[3];
  const float* W2 = (const float*)d_in[4];
  const float* b2 = (const float*)d_in[5];
  const int* src = ei;
  const int* dst = ei + N_EDGES;
  float* out = (float*)d_out;

  char* ws = (char*)d_ws;
  // ws layout (16B aligned):
  float*          dinv    = (float*)(ws + 0);          // 200000 B
  int*            count   = (int*)  (ws + 200704);     // 200000 B
  int*            cursor  = (int*)  (ws + 401408);     // 200000 B
  int*            row_ptr = (int*)  (ws + 602112);     // 200004 B
  int*            csr_src = (int*)  (ws + 802816);     // 3200000 B
  unsigned short* W1t     = (unsigned short*)(ws + 4002816);  // 131072 B
  float*          t2      = (float*)(ws + 4133888);    // 600000 B
  int*            local_pre = (int*)(ws + 4733952);    // 200000 B
  int*            blocksum  = (int*)(ws + 4935680);    // 784 B
  int*            blockoff  = (int*)(ws + 4936704);    // 784 B
  unsigned short* h1b     = (unsigned short*)(ws + 4937728);  // 12800000 B (end ~17.7 MB)

  k_zero  <<<(N_NODES + 255) / 256, 256, 0, stream>>>(count);
  k_hist  <<<(N_EDGES + 255) / 256, 256, 0, stream>>>(dst, count);
  k_scan1 <<<NBLK_SCAN, 256, 0, stream>>>(count, local_pre, blocksum);
  k_scan2 <<<1, 256, 0, stream>>>(blocksum, blockoff);
  k_scan3 <<<NBLK_SCAN, 256, 0, stream>>>(count, local_pre, blockoff, row_ptr, cursor, dinv);
  k_fill  <<<(N_EDGES + 255) / 256, 256, 0, stream>>>(src, dst, cursor, csr_src);
  k_w1t   <<<(F_IN * F_HID + 255) / 256, 256, 0, stream>>>(W1, W1t);
  k_gemm1 <<<(N_NODES + BM - 1) / BM, 256, 0, stream>>>(x, W1t, h1b);
  k_agg1_fused<<<N_NODES / 4, 256, 0, stream>>>(row_ptr, csr_src, dinv, h1b, b1, W2, t2);
  k_agg2  <<<(N_NODES + 15) / 16, 256, 0, stream>>>(row_ptr, csr_src, dinv, t2, b2, out);
}

// Round 7
// 199.300 us; speedup vs baseline: 1.0399x; 1.0399x over previous
//
#include <hip/hip_runtime.h>
#include <stdint.h>

#define N_NODES 50000
#define N_EDGES 800000
#define F_IN    512
#define F_HID   128
#define F_OUT   3
#define NBLK_SCAN 196  // ceil(50000/256)

typedef __attribute__((ext_vector_type(8))) short short8;
typedef __attribute__((ext_vector_type(4))) float f32x4;

__device__ __forceinline__ unsigned short f2bf(float f) {
  union { float f; unsigned u; } v; v.f = f;
  unsigned r = v.u + 0x7FFFu + ((v.u >> 16) & 1u);
  return (unsigned short)(r >> 16);
}

// ---- prep: zero degree counters + W1 -> bf16 transposed [n][k] -------------
__global__ __launch_bounds__(256) void k_prep(const float* __restrict__ W1,
                                              unsigned short* __restrict__ W1t,
                                              int* __restrict__ count) {
  int idx = blockIdx.x * 256 + threadIdx.x;
  if (idx < N_NODES) count[idx] = 0;
  if (idx < F_IN * F_HID) {
    int k = idx >> 7;    // W1 is [512][128] row-major
    int n = idx & 127;
    W1t[n * F_IN + k] = f2bf(W1[idx]);
  }
}

__global__ __launch_bounds__(256) void k_hist(const int* __restrict__ dst,
                                              int* __restrict__ count) {
  int e = blockIdx.x * 256 + threadIdx.x;
  if (e < N_EDGES) atomicAdd(&count[dst[e]], 1);
}

// hierarchical scan, stage 1: per-block exclusive prefix + block sums
__global__ __launch_bounds__(256) void k_scan1(const int* __restrict__ count,
                                               int* __restrict__ local_pre,
                                               int* __restrict__ blocksum) {
  __shared__ int s[256];
  int t = threadIdx.x;
  int i = blockIdx.x * 256 + t;
  int v = (i < N_NODES) ? count[i] : 0;
  s[t] = v;
  __syncthreads();
  #pragma unroll
  for (int off = 1; off < 256; off <<= 1) {
    int u = (t >= off) ? s[t - off] : 0;
    __syncthreads();
    s[t] += u;
    __syncthreads();
  }
  if (i < N_NODES) local_pre[i] = s[t] - v;  // exclusive
  if (t == 255) blocksum[blockIdx.x] = s[255];
}

// stage 2: single small block scans the 196 block sums (exclusive)
__global__ __launch_bounds__(256) void k_scan2(const int* __restrict__ blocksum,
                                               int* __restrict__ blockoff) {
  __shared__ int s[256];
  int t = threadIdx.x;
  int v = (t < NBLK_SCAN) ? blocksum[t] : 0;
  s[t] = v;
  __syncthreads();
  #pragma unroll
  for (int off = 1; off < 256; off <<= 1) {
    int u = (t >= off) ? s[t - off] : 0;
    __syncthreads();
    s[t] += u;
    __syncthreads();
  }
  if (t < NBLK_SCAN) blockoff[t] = s[t] - v;
}

// stage 3: finalize row_ptr / cursor / dinv
__global__ __launch_bounds__(256) void k_scan3(const int* __restrict__ count,
                                               const int* __restrict__ local_pre,
                                               const int* __restrict__ blockoff,
                                               int* __restrict__ row_ptr,
                                               int* __restrict__ cursor,
                                               float* __restrict__ dinv) {
  int i = blockIdx.x * 256 + threadIdx.x;
  if (i < N_NODES) {
    int r = local_pre[i] + blockoff[blockIdx.x];
    row_ptr[i] = r;
    cursor[i]  = r;
    dinv[i] = rsqrtf((float)(count[i] + 1));
  }
  if (i == 0) row_ptr[N_NODES] = N_EDGES;
}

__global__ __launch_bounds__(256) void k_fill(const int* __restrict__ src,
                                              const int* __restrict__ dst,
                                              int* __restrict__ cursor,
                                              int* __restrict__ csr_src) {
  int e = blockIdx.x * 256 + threadIdx.x;
  if (e >= N_EDGES) return;
  int d = dst[e];
  int pos = atomicAdd(&cursor[d], 1);
  csr_src[pos] = src[e];
}

// ---- GEMM1: h1' = dinv .* (x @ W1)  (bf16 MFMA, f32 acc; bf16 out) ---------
// Pre-scaling each row by its own dinv removes the per-edge dinv[s] gather
// from BOTH aggregation kernels: norm*h[s] = dinv[d] * (dinv[s]*h[s]).
#define BM 128
#define BK 64
#define LPAD 72  // 144 B/row breaks the stride-128B bank conflict

__global__ __launch_bounds__(256) void k_gemm1(const float* __restrict__ x,
                                               const unsigned short* __restrict__ W1t,
                                               const float* __restrict__ dinv,
                                               unsigned short* __restrict__ h1b) {
  __shared__ unsigned short As[BM * LPAD];
  __shared__ unsigned short Bs[F_HID * LPAD];
  const int t = threadIdx.x;
  const int lane = t & 63;
  const int wid = t >> 6;
  const int row0 = blockIdx.x * BM;

  f32x4 acc[2][8];
  #pragma unroll
  for (int i = 0; i < 2; ++i)
    #pragma unroll
    for (int j = 0; j < 8; ++j) acc[i][j] = (f32x4)0.0f;

  const int lane15 = lane & 15;
  const int kgrp = (lane >> 4) << 3;
  const int wrow = wid << 5;

  for (int k0 = 0; k0 < F_IN; k0 += BK) {
    #pragma unroll
    for (int r = 0; r < 8; ++r) {
      int f = (r << 8) + t;
      int row = f >> 4;
      int c4 = (f & 15) << 2;
      int grow = row0 + row;
      grow = grow < N_NODES ? grow : N_NODES - 1;  // clamp tail (store guarded)
      const float4 v = *reinterpret_cast<const float4*>(x + (size_t)grow * F_IN + k0 + c4);
      ushort4 b;
      b.x = f2bf(v.x); b.y = f2bf(v.y); b.z = f2bf(v.z); b.w = f2bf(v.w);
      *reinterpret_cast<ushort4*>(&As[row * LPAD + c4]) = b;
    }
    #pragma unroll
    for (int r = 0; r < 8; ++r) {
      int g = (r << 8) + t;
      int n = g >> 4;
      int c4 = (g & 15) << 2;
      ushort4 wv = *reinterpret_cast<const ushort4*>(W1t + n * F_IN + k0 + c4);
      *reinterpret_cast<ushort4*>(&Bs[n * LPAD + c4]) = wv;
    }
    __syncthreads();
    #pragma unroll
    for (int ks = 0; ks < 2; ++ks) {
      const int kk = (ks << 5) + kgrp;
      short8 a0 = *reinterpret_cast<const short8*>(&As[(wrow + lane15) * LPAD + kk]);
      short8 a1 = *reinterpret_cast<const short8*>(&As[(wrow + 16 + lane15) * LPAD + kk]);
      #pragma unroll
      for (int nr = 0; nr < 8; ++nr) {
        short8 b = *reinterpret_cast<const short8*>(&Bs[(nr * 16 + lane15) * LPAD + kk]);
        acc[0][nr] = __builtin_amdgcn_mfma_f32_16x16x32_bf16(a0, b, acc[0][nr], 0, 0, 0);
        acc[1][nr] = __builtin_amdgcn_mfma_f32_16x16x32_bf16(a1, b, acc[1][nr], 0, 0, 0);
      }
    }
    __syncthreads();
  }
  const int rgrp = (lane >> 4) << 2;
  #pragma unroll
  for (int mr = 0; mr < 2; ++mr) {
    const int rowb = row0 + wrow + mr * 16 + rgrp;
    #pragma unroll
    for (int nr = 0; nr < 8; ++nr) {
      const int col = nr * 16 + lane15;
      #pragma unroll
      for (int r = 0; r < 4; ++r) {
        const int row = rowb + r;
        if (row < N_NODES)
          h1b[(size_t)row * F_HID + col] = f2bf(dinv[row] * acc[mr][nr][r]);
      }
    }
  }
}

// ---- layer-1 gather + bias + ReLU + GEMM2 fused: wave per node ------------
// Proven shape (two 32-lane groups, 4 features/lane, stride-2 interleave),
// bf16 rows via uint2. NEW: rows pre-scaled -> inner loop is unweighted add,
// no dinv gather; unroll-4 -> 4 independent row loads in flight per group.
__global__ __launch_bounds__(256) void k_agg1_fused(const int* __restrict__ row_ptr,
                                                    const int* __restrict__ csr_src,
                                                    const float* __restrict__ dinv,
                                                    const unsigned short* __restrict__ h1b,
                                                    const float* __restrict__ b1,
                                                    const float* __restrict__ W2,
                                                    float* __restrict__ t2) {
  int t = threadIdx.x;
  int lane = t & 63;
  int node = blockIdx.x * 4 + (t >> 6);  // 50000 = 12500*4, no tail
  int g = lane >> 5;
  int fl = (lane & 31) << 2;
  float dd = dinv[node];
  f32x4 acc = (f32x4)0.0f;
  if (g == 0) {  // self loop: dd * h1'[node] = dd*dinv[node]*h1 = dinv^2 h1 after final scale
    const uint2 sv = *reinterpret_cast<const uint2*>(h1b + (size_t)node * F_HID + fl);
    acc[0] = __uint_as_float(sv.x << 16);
    acc[1] = __uint_as_float(sv.x & 0xFFFF0000u);
    acc[2] = __uint_as_float(sv.y << 16);
    acc[3] = __uint_as_float(sv.y & 0xFFFF0000u);
  }
  int start = row_ptr[node], end = row_ptr[node + 1];
  int i = start + g;
  // unroll-4: edges i, i+2, i+4, i+6 -> 4 rows in flight per group
  for (; i + 6 < end; i += 8) {
    int s0 = csr_src[i];
    int s1 = csr_src[i + 2];
    int s2 = csr_src[i + 4];
    int s3 = csr_src[i + 6];
    const uint2 v0 = *reinterpret_cast<const uint2*>(h1b + (size_t)s0 * F_HID + fl);
    const uint2 v1 = *reinterpret_cast<const uint2*>(h1b + (size_t)s1 * F_HID + fl);
    const uint2 v2 = *reinterpret_cast<const uint2*>(h1b + (size_t)s2 * F_HID + fl);
    const uint2 v3 = *reinterpret_cast<const uint2*>(h1b + (size_t)s3 * F_HID + fl);
    acc[0] += __uint_as_float(v0.x << 16);
    acc[1] += __uint_as_float(v0.x & 0xFFFF0000u);
    acc[2] += __uint_as_float(v0.y << 16);
    acc[3] += __uint_as_float(v0.y & 0xFFFF0000u);
    acc[0] += __uint_as_float(v1.x << 16);
    acc[1] += __uint_as_float(v1.x & 0xFFFF0000u);
    acc[2] += __uint_as_float(v1.y << 16);
    acc[3] += __uint_as_float(v1.y & 0xFFFF0000u);
    acc[0] += __uint_as_float(v2.x << 16);
    acc[1] += __uint_as_float(v2.x & 0xFFFF0000u);
    acc[2] += __uint_as_float(v2.y << 16);
    acc[3] += __uint_as_float(v2.y & 0xFFFF0000u);
    acc[0] += __uint_as_float(v3.x << 16);
    acc[1] += __uint_as_float(v3.x & 0xFFFF0000u);
    acc[2] += __uint_as_float(v3.y << 16);
    acc[3] += __uint_as_float(v3.y & 0xFFFF0000u);
  }
  for (; i < end; i += 2) {
    int s = csr_src[i];
    const uint2 v = *reinterpret_cast<const uint2*>(h1b + (size_t)s * F_HID + fl);
    acc[0] += __uint_as_float(v.x << 16);
    acc[1] += __uint_as_float(v.x & 0xFFFF0000u);
    acc[2] += __uint_as_float(v.y << 16);
    acc[3] += __uint_as_float(v.y & 0xFFFF0000u);
  }
  // combine the two edge-groups: lanes 0-31 += lanes 32-63
  #pragma unroll
  for (int j = 0; j < 4; ++j) {
    float o = __shfl(acc[j], (lane & 31) + 32);
    acc[j] += o;
  }
  // features = b1 + dd * acc; relu
  const float4 bb = *reinterpret_cast<const float4*>(b1 + fl);
  float v0 = fmaxf(fmaf(dd, acc[0], bb.x), 0.0f);
  float v1 = fmaxf(fmaf(dd, acc[1], bb.y), 0.0f);
  float v2 = fmaxf(fmaf(dd, acc[2], bb.z), 0.0f);
  float v3 = fmaxf(fmaf(dd, acc[3], bb.w), 0.0f);
  // 128->3 dot products; W2 is [128][3] row-major; store t2' = dinv[node]*t2
  const float* w2r = W2 + fl * 3;
  #pragma unroll
  for (int c = 0; c < 3; ++c) {
    float p = v0 * w2r[c] + v1 * w2r[3 + c] + v2 * w2r[6 + c] + v3 * w2r[9 + c];
    p += __shfl_down(p, 16);
    p += __shfl_down(p, 8);
    p += __shfl_down(p, 4);
    p += __shfl_down(p, 2);
    p += __shfl_down(p, 1);
    if (lane == 0) t2[(size_t)node * 3 + c] = dd * p;
  }
}

// ---- layer-2 gather: 16 lanes per node; t2 rows pre-scaled -----------------
__global__ __launch_bounds__(256) void k_agg2(const int* __restrict__ row_ptr,
                                              const int* __restrict__ csr_src,
                                              const float* __restrict__ dinv,
                                              const float* __restrict__ t2,
                                              const float* __restrict__ b2,
                                              float* __restrict__ out) {
  int t = threadIdx.x;
  int node = blockIdx.x * 16 + (t >> 4);
  if (node >= N_NODES) return;
  int sl = t & 15;
  float a0 = 0.f, a1 = 0.f, a2 = 0.f;
  int start = row_ptr[node], end = row_ptr[node + 1];
  for (int i = start + sl; i < end; i += 16) {
    int s = csr_src[i];
    a0 += t2[s * 3 + 0];
    a1 += t2[s * 3 + 1];
    a2 += t2[s * 3 + 2];
  }
  #pragma unroll
  for (int off = 8; off > 0; off >>= 1) {
    a0 += __shfl_down(a0, off);
    a1 += __shfl_down(a1, off);
    a2 += __shfl_down(a2, off);
  }
  if (sl == 0) {
    float dd = dinv[node];
    out[node * 3 + 0] = fmaf(dd, t2[node * 3 + 0] + a0, b2[0]);
    out[node * 3 + 1] = fmaf(dd, t2[node * 3 + 1] + a1, b2[1]);
    out[node * 3 + 2] = fmaf(dd, t2[node * 3 + 2] + a2, b2[2]);
  }
}

extern "C" void kernel_launch(void* const* d_in, const int* in_sizes, int n_in,
                              void* d_out, int out_size, void* d_ws, size_t ws_size,
                              hipStream_t stream) {
  const float* x  = (const float*)d_in[0];
  const int*   ei = (const int*)d_in[1];
  const float* W1 = (const float*)d_in[2];
  const float* b1 = (const float*)d_in[3];
  const float* W2 = (const float*)d_in[4];
  const float* b2 = (const float*)d_in[5];
  const int* src = ei;
  const int* dst = ei + N_EDGES;
  float* out = (float*)d_out;

  char* ws = (char*)d_ws;
  // ws layout (16B aligned):
  float*          dinv    = (float*)(ws + 0);          // 200000 B
  int*            count   = (int*)  (ws + 200704);     // 200000 B
  int*            cursor  = (int*)  (ws + 401408);     // 200000 B
  int*            row_ptr = (int*)  (ws + 602112);     // 200004 B
  int*            csr_src = (int*)  (ws + 802816);     // 3200000 B
  unsigned short* W1t     = (unsigned short*)(ws + 4002816);  // 131072 B
  float*          t2      = (float*)(ws + 4133888);    // 600000 B
  int*            local_pre = (int*)(ws + 4733952);    // 200000 B
  int*            blocksum  = (int*)(ws + 4935680);    // 784 B
  int*            blockoff  = (int*)(ws + 4936704);    // 784 B
  unsigned short* h1b     = (unsigned short*)(ws + 4937728);  // 12800000 B (end ~17.7 MB)

  k_prep  <<<(F_IN * F_HID + 255) / 256, 256, 0, stream>>>(W1, W1t, count);
  k_hist  <<<(N_EDGES + 255) / 256, 256, 0, stream>>>(dst, count);
  k_scan1 <<<NBLK_SCAN, 256, 0, stream>>>(count, local_pre, blocksum);
  k_scan2 <<<1, 256, 0, stream>>>(blocksum, blockoff);
  k_scan3 <<<NBLK_SCAN, 256, 0, stream>>>(count, local_pre, blockoff, row_ptr, cursor, dinv);
  k_fill  <<<(N_EDGES + 255) / 256, 256, 0, stream>>>(src, dst, cursor, csr_src);
  k_gemm1 <<<(N_NODES + BM - 1) / BM, 256, 0, stream>>>(x, W1t, dinv, h1b);
  k_agg1_fused<<<N_NODES / 4, 256, 0, stream>>>(row_ptr, csr_src, dinv, h1b, b1, W2, t2);
  k_agg2  <<<(N_NODES + 15) / 16, 256, 0, stream>>>(row_ptr, csr_src, dinv, t2, b2, out);
}